// Round 3
// baseline (455.806 us; speedup 1.0000x reference)
//
#include <hip/hip_runtime.h>
#include <hip/hip_cooperative_groups.h>
#include <math.h>

// I-BERT IntSoftmax, exact-numerics replication of the JAX reference.
// x: (1,12,2048,2048) f32; 24576 rows of S=2048.
// R6: single cooperative kernel. Phase 1: per-block partial amax (distinct
//     addresses, agent-scope stores — NOT R4's same-line atomic storm).
//     grid.sync(). Phase 1b: every thread reduces partials (max is order-
//     independent => bit-exact) and computes Scalars in registers. Phase 2:
//     proven wave-per-row body (38us), grid-strided over row groups.
//     Removes k_scalars node + 2 inter-kernel gaps + 2 grid ramp/drains.
//     Fallback to the R5 3-kernel path if cooperative launch is rejected.

#define ROW_S 2048
#define MM_BLOCKS 2048
#define MM_STRIDE (MM_BLOCKS * 256)

namespace cg = cooperative_groups;

typedef float floatx4 __attribute__((ext_vector_type(4)));

struct Scalars {
    double exp_sf_d;
    double inv_exp_sf;
    double m_int;
    double inv_pow;
    float  sf;
    float  inv_sf;
    float  x0_int;
    float  inv_x0;
    float  b_int;
    float  c_int;
    float  thirty_x0;
    float  _pad;
};

// Markstein: with inv = RN(1/b), returns RN(a/b) bit-exactly.
__device__ __forceinline__ float div_rn(float a, float b, float inv) {
    const float q0 = __fmul_rn(a, inv);
    const float r  = __fmaf_rn(-b, q0, a);
    return __fmaf_rn(r, inv, q0);
}
__device__ __forceinline__ double ddiv_rn(double a, double b, double inv) {
    const double q0 = __dmul_rn(a, inv);
    const double r  = __fma_rn(-b, q0, a);
    return __fma_rn(r, inv, q0);
}

// ---------------------------------------------------------------------------
// Fused cooperative kernel
// ---------------------------------------------------------------------------
__global__ __launch_bounds__(256) void k_fused(const float* __restrict__ x,
                                               float* __restrict__ out,
                                               float* __restrict__ pmax,
                                               int n4, int ngroups) {
    const int tid  = threadIdx.x;
    const int lane = tid & 63, wave = tid >> 6;
    const int G    = gridDim.x;
    __shared__ float sred[4];

    // ---- phase 1: per-block partial max|x| over grid-stride slice ----
    {
        const float4* x4 = (const float4*)x;
        const int stride = G * 256;
        float am = 0.0f;
        int i = blockIdx.x * 256 + tid;
        for (; i + 3 * stride < n4; i += 4 * stride) {
            const float4 v0 = x4[i];
            const float4 v1 = x4[i + stride];
            const float4 v2 = x4[i + 2 * stride];
            const float4 v3 = x4[i + 3 * stride];
            const float m0 = fmaxf(fmaxf(fabsf(v0.x), fabsf(v0.y)), fmaxf(fabsf(v0.z), fabsf(v0.w)));
            const float m1 = fmaxf(fmaxf(fabsf(v1.x), fabsf(v1.y)), fmaxf(fabsf(v1.z), fabsf(v1.w)));
            const float m2 = fmaxf(fmaxf(fabsf(v2.x), fabsf(v2.y)), fmaxf(fabsf(v2.z), fabsf(v2.w)));
            const float m3 = fmaxf(fmaxf(fabsf(v3.x), fabsf(v3.y)), fmaxf(fabsf(v3.z), fabsf(v3.w)));
            am = fmaxf(am, fmaxf(fmaxf(m0, m1), fmaxf(m2, m3)));
        }
        for (; i < n4; i += stride) {
            const float4 v = x4[i];
            am = fmaxf(am, fmaxf(fmaxf(fabsf(v.x), fabsf(v.y)), fmaxf(fabsf(v.z), fabsf(v.w))));
        }
#pragma unroll
        for (int m = 32; m > 0; m >>= 1) am = fmaxf(am, __shfl_xor(am, m));
        if (lane == 0) sred[wave] = am;
        __syncthreads();
        if (tid == 0) {
            const float bm = fmaxf(fmaxf(sred[0], sred[1]), fmaxf(sred[2], sred[3]));
            __hip_atomic_store(&pmax[blockIdx.x], bm,
                               __ATOMIC_RELEASE, __HIP_MEMORY_SCOPE_AGENT);
        }
    }
    cg::this_grid().sync();

    // ---- phase 1b: every thread reduces G partials and derives Scalars ----
    // (fmax is exact & order-independent => identical bits in every thread)
    float am = 0.0f;
    for (int i = tid; i < G; i += 256)
        am = fmaxf(am, __hip_atomic_load(&pmax[i],
                       __ATOMIC_RELAXED, __HIP_MEMORY_SCOPE_AGENT));
#pragma unroll
    for (int m = 32; m > 0; m >>= 1) am = fmaxf(am, __shfl_xor(am, m));
    if (lane == 0) sred[wave] = am;
    __syncthreads();
    const float sabs = fmaxf(fmaxf(sred[0], sred[1]), fmaxf(sred[2], sred[3]));

    // sym_scale(x.min, x.max, 16) via max|x|, all f32 like the reference
    const float sf     = __fdiv_rn(fmaxf(sabs, 1e-8f), 32767.0f);
    const float x0i    = floorf(__fdiv_rn((float)(-0.6931), sf));
    const float sfsq   = __fmul_rn(sf, sf);
    const float b_int  = floorf(__fdiv_rn((float)(0.96963238 / 0.35815147), sf));
    const float c_int  = floorf(__fdiv_rn((float)(1.0 / 0.35815147), sfsq));
    const float exp_sf = __fdiv_rn(__fmul_rn((float)(0.35815147), sfsq), 1073741824.0f);
    // global max of exp_int is exactly c_int * 2^30 (row-max element:
    // r=0,q=0 => z=c_int); min>=0, so sym_scale uses this max.
    const float emax   = __fmul_rn(c_int, 1073741824.0f);
    const float act_sf = __fdiv_rn(fmaxf(emax, 1e-8f), 32767.0f);
    // fixedpoint_mul scalar part (f64, per reference)
    const float  nsf = __fdiv_rn(exp_sf, act_sf);
    const double ns  = (double)nsf;
    int E;
    (void)frexp(ns, &E);                      // e = floor(log2(ns)) + 1 == E
    const double m_int      = rint(ldexp(ns, 31 - E));
    const double inv_pow    = ldexp(1.0, E - 31);          // exact pow2
    const double exp_sf_d   = (double)exp_sf;
    const double inv_exp_sf = 1.0 / exp_sf_d;              // RN f64 reciprocal
    const float  inv_sf     = __fdiv_rn(1.0f, sf);
    const float  inv_x0     = __fdiv_rn(1.0f, x0i);
    const float  thirty_x0  = __fmul_rn(30.0f, x0i);       // exact (int < 2^24)

    // ---- phase 2: wave-per-row, 32 elements/lane, grid-stride row groups ----
    for (int g = blockIdx.x; g < ngroups; g += G) {
        const size_t row = (size_t)g * 4 + wave;
        const floatx4* x4r = (const floatx4*)(x + row * ROW_S);
        floatx4* o4 = (floatx4*)(out + row * ROW_S);

        floatx4 v[8];
#pragma unroll
        for (int i = 0; i < 8; ++i) v[i] = x4r[i * 64 + lane];

        // raw row max (quant chain is monotone => ximax = quant(raw max))
        float rmax = -INFINITY;
#pragma unroll
        for (int i = 0; i < 8; ++i) {
#pragma unroll
            for (int c = 0; c < 4; ++c) rmax = fmaxf(rmax, v[i][c]);
        }
#pragma unroll
        for (int m = 32; m > 0; m >>= 1) rmax = fmaxf(rmax, __shfl_xor(rmax, m));

        float t = rintf(div_rn(rmax, sf, inv_sf));
        t = fminf(fmaxf(t, -32768.0f), 32767.0f);
        t = __fmul_rn(t, sf);
        const float ximax = div_rn(t, sf, inv_sf);

        float ssum = 0.0f;
#pragma unroll
        for (int i = 0; i < 8; ++i) {
#pragma unroll
            for (int c = 0; c < 4; ++c) {
                // QuantAct(16): x_int = clip(rint(x/sf)); xi = (x_int*sf)/sf
                float q = rintf(div_rn(v[i][c], sf, inv_sf));
                q = fminf(fmaxf(q, -32768.0f), 32767.0f);
                q = __fmul_rn(q, sf);
                const float xi = div_rn(q, sf, inv_sf);
                const float xs = __fsub_rn(xi, ximax);
                const float xm = fmaxf(xs, thirty_x0);
                const float qf = floorf(div_rn(xm, x0i, inv_x0));
                const float r  = __fsub_rn(xm, __fmul_rn(x0i, qf));
                // z = r*(r+b)+c — must NOT contract to FMA
                const float z  = __fadd_rn(__fmul_rn(r, __fadd_rn(r, b_int)), c_int);
                const int   qi = (int)qf;                          // in [0,30]
                const float p2 = __int_as_float((157 - qi) << 23); // 2^(30-qi)
                const float ei = fmaxf(floorf(__fmul_rn(z, p2)), 0.0f);
                // fixedpoint_mul in f64 (reference runs in double)
                const double a  = (double)ei;
                const double zi = rint(ddiv_rn(a, exp_sf_d, inv_exp_sf));
                double ovd = rint(__dmul_rn(__dmul_rn(zi, m_int), inv_pow));
                ovd = fmin(fmax(ovd, -32768.0), 32767.0);
                const float e16 = (float)ovd;   // integer-valued, exact
                v[i][c] = e16;
                ssum += e16;  // non-neg ints, row sum < 2^24 -> order-free
            }
        }
#pragma unroll
        for (int m = 32; m > 0; m >>= 1) ssum += __shfl_xor(ssum, m);
        const float factor = floorf(__fdiv_rn(4294967296.0f, ssum));

#pragma unroll
        for (int i = 0; i < 8; ++i) {
            floatx4 w;
#pragma unroll
            for (int c = 0; c < 4; ++c) {
                const float oi = floorf(__fmul_rn(__fmul_rn(v[i][c], factor),
                                                  5.9604644775390625e-8f));
                w[c] = __fmul_rn(oi, 0.00390625f);
            }
            __builtin_nontemporal_store(w, &o4[i * 64 + lane]);
        }
    }
}

// ---------------------------------------------------------------------------
// Fallback path (R5 3-kernel structure) — used if cooperative launch rejected
// ---------------------------------------------------------------------------
__global__ __launch_bounds__(256) void k_amax(const float* __restrict__ x,
                                              float* __restrict__ pmax,
                                              int n4) {
    const int tid = threadIdx.x;
    const float4* x4 = (const float4*)x;
    float am = 0.0f;
    int i = blockIdx.x * 256 + tid;
    for (; i + 3 * MM_STRIDE < n4; i += 4 * MM_STRIDE) {
        const float4 v0 = x4[i];
        const float4 v1 = x4[i + MM_STRIDE];
        const float4 v2 = x4[i + 2 * MM_STRIDE];
        const float4 v3 = x4[i + 3 * MM_STRIDE];
        const float m0 = fmaxf(fmaxf(fabsf(v0.x), fabsf(v0.y)), fmaxf(fabsf(v0.z), fabsf(v0.w)));
        const float m1 = fmaxf(fmaxf(fabsf(v1.x), fabsf(v1.y)), fmaxf(fabsf(v1.z), fabsf(v1.w)));
        const float m2 = fmaxf(fmaxf(fabsf(v2.x), fabsf(v2.y)), fmaxf(fabsf(v2.z), fabsf(v2.w)));
        const float m3 = fmaxf(fmaxf(fabsf(v3.x), fabsf(v3.y)), fmaxf(fabsf(v3.z), fabsf(v3.w)));
        am = fmaxf(am, fmaxf(fmaxf(m0, m1), fmaxf(m2, m3)));
    }
    for (; i < n4; i += MM_STRIDE) {
        const float4 v = x4[i];
        am = fmaxf(am, fmaxf(fmaxf(fabsf(v.x), fabsf(v.y)), fmaxf(fabsf(v.z), fabsf(v.w))));
    }
#pragma unroll
    for (int m = 32; m > 0; m >>= 1) am = fmaxf(am, __shfl_xor(am, m));
    __shared__ float sred[4];
    const int wave = tid >> 6, lane = tid & 63;
    if (lane == 0) sred[wave] = am;
    __syncthreads();
    if (tid == 0)
        pmax[blockIdx.x] = fmaxf(fmaxf(sred[0], sred[1]), fmaxf(sred[2], sred[3]));
}

__global__ __launch_bounds__(256) void k_scalars(const float* __restrict__ pmax,
                                                 Scalars* __restrict__ sc) {
    const int tid = threadIdx.x;
    float am = 0.0f;
    for (int i = tid; i < MM_BLOCKS; i += 256) am = fmaxf(am, pmax[i]);
#pragma unroll
    for (int m = 32; m > 0; m >>= 1) am = fmaxf(am, __shfl_xor(am, m));
    __shared__ float sred[4];
    const int wave = tid >> 6, lane = tid & 63;
    if (lane == 0) sred[wave] = am;
    __syncthreads();
    if (tid == 0) {
        const float sabs = fmaxf(fmaxf(sred[0], sred[1]), fmaxf(sred[2], sred[3]));
        const float sf    = __fdiv_rn(fmaxf(sabs, 1e-8f), 32767.0f);
        const float x0i   = floorf(__fdiv_rn((float)(-0.6931), sf));
        const float sfsq  = __fmul_rn(sf, sf);
        const float b_int = floorf(__fdiv_rn((float)(0.96963238 / 0.35815147), sf));
        const float c_int = floorf(__fdiv_rn((float)(1.0 / 0.35815147), sfsq));
        const float exp_sf = __fdiv_rn(__fmul_rn((float)(0.35815147), sfsq), 1073741824.0f);
        const float emax   = __fmul_rn(c_int, 1073741824.0f);
        const float act_sf = __fdiv_rn(fmaxf(emax, 1e-8f), 32767.0f);
        const float  nsf = __fdiv_rn(exp_sf, act_sf);
        const double ns  = (double)nsf;
        int E;
        (void)frexp(ns, &E);
        const double m_int = rint(ldexp(ns, 31 - E));
        sc->exp_sf_d   = (double)exp_sf;
        sc->inv_exp_sf = 1.0 / (double)exp_sf;
        sc->m_int      = m_int;
        sc->inv_pow    = ldexp(1.0, E - 31);
        sc->sf         = sf;
        sc->inv_sf     = __fdiv_rn(1.0f, sf);
        sc->x0_int     = x0i;
        sc->inv_x0     = __fdiv_rn(1.0f, x0i);
        sc->b_int      = b_int;
        sc->c_int      = c_int;
        sc->thirty_x0  = __fmul_rn(30.0f, x0i);
    }
}

__global__ __launch_bounds__(256) void k_row(const float* __restrict__ x,
                                             float* __restrict__ out,
                                             const Scalars* __restrict__ scp) {
    const int lane = threadIdx.x & 63;
    const int wave = threadIdx.x >> 6;
    const size_t row = (size_t)blockIdx.x * 4 + wave;
    const floatx4* x4 = (const floatx4*)(x + row * ROW_S);
    floatx4* o4 = (floatx4*)(out + row * ROW_S);

    floatx4 v[8];
#pragma unroll
    for (int i = 0; i < 8; ++i) v[i] = x4[i * 64 + lane];

    const Scalars sc = *scp;
    const float sf = sc.sf, inv_sf = sc.inv_sf;

    float rmax = -INFINITY;
#pragma unroll
    for (int i = 0; i < 8; ++i) {
#pragma unroll
        for (int c = 0; c < 4; ++c) rmax = fmaxf(rmax, v[i][c]);
    }
#pragma unroll
    for (int m = 32; m > 0; m >>= 1) rmax = fmaxf(rmax, __shfl_xor(rmax, m));

    float t = rintf(div_rn(rmax, sf, inv_sf));
    t = fminf(fmaxf(t, -32768.0f), 32767.0f);
    t = __fmul_rn(t, sf);
    const float ximax = div_rn(t, sf, inv_sf);

    float ssum = 0.0f;
#pragma unroll
    for (int i = 0; i < 8; ++i) {
#pragma unroll
        for (int c = 0; c < 4; ++c) {
            float q = rintf(div_rn(v[i][c], sf, inv_sf));
            q = fminf(fmaxf(q, -32768.0f), 32767.0f);
            q = __fmul_rn(q, sf);
            const float xi = div_rn(q, sf, inv_sf);
            const float xs = __fsub_rn(xi, ximax);
            const float xm = fmaxf(xs, sc.thirty_x0);
            const float qf = floorf(div_rn(xm, sc.x0_int, sc.inv_x0));
            const float r  = __fsub_rn(xm, __fmul_rn(sc.x0_int, qf));
            const float z  = __fadd_rn(__fmul_rn(r, __fadd_rn(r, sc.b_int)), sc.c_int);
            const int   qi = (int)qf;
            const float p2 = __int_as_float((157 - qi) << 23);
            const float ei = fmaxf(floorf(__fmul_rn(z, p2)), 0.0f);
            const double a  = (double)ei;
            const double zi = rint(ddiv_rn(a, sc.exp_sf_d, sc.inv_exp_sf));
            double ovd = rint(__dmul_rn(__dmul_rn(zi, sc.m_int), sc.inv_pow));
            ovd = fmin(fmax(ovd, -32768.0), 32767.0);
            const float e16 = (float)ovd;
            v[i][c] = e16;
            ssum += e16;
        }
    }
#pragma unroll
    for (int m = 32; m > 0; m >>= 1) ssum += __shfl_xor(ssum, m);
    const float factor = floorf(__fdiv_rn(4294967296.0f, ssum));

#pragma unroll
    for (int i = 0; i < 8; ++i) {
        floatx4 w;
#pragma unroll
        for (int c = 0; c < 4; ++c) {
            const float oi = floorf(__fmul_rn(__fmul_rn(v[i][c], factor), 5.9604644775390625e-8f));
            w[c] = __fmul_rn(oi, 0.00390625f);
        }
        __builtin_nontemporal_store(w, &o4[i * 64 + lane]);
    }
}

extern "C" void kernel_launch(void* const* d_in, const int* in_sizes, int n_in,
                              void* d_out, int out_size, void* d_ws, size_t ws_size,
                              hipStream_t stream) {
    const float* x = (const float*)d_in[0];
    float* out = (float*)d_out;
    const int n = in_sizes[0];          // 50331648
    const int rows = n / ROW_S;         // 24576
    int n4 = n / 4;
    int ngroups = rows / 4;             // 6144

    // Size cooperative grid once: co-residency capacity, snapped to a divisor
    // of 6144 so phase-2 has zero row-group imbalance.
    static int G = 0;
    if (G == 0) {
        int maxb = 0;
        if (hipOccupancyMaxActiveBlocksPerMultiprocessor(
                &maxb, reinterpret_cast<const void*>(k_fused), 256, 0) != hipSuccess ||
            maxb <= 0)
            maxb = 4;
        int dev = 0, ncu = 0;
        hipGetDevice(&dev);
        if (hipDeviceGetAttribute(&ncu, hipDeviceAttributeMultiprocessorCount, dev) != hipSuccess ||
            ncu <= 0)
            ncu = 256;
        const long cap = (long)maxb * ncu;
        const int snaps[] = {2048, 1536, 1024, 768, 512, 384, 256};
        G = 256;
        for (int s : snaps) { if (cap >= s) { G = s; break; } }
    }

    float* pmaxc = (float*)d_ws;        // G floats (<= 8 KiB)
    void* args[] = {(void*)&x, (void*)&out, (void*)&pmaxc, (void*)&n4, (void*)&ngroups};
    const hipError_t e = hipLaunchCooperativeKernel(
        reinterpret_cast<const void*>(k_fused), dim3(G), dim3(256), args, 0, stream);
    if (e == hipSuccess) return;

    // Fallback: R5 3-kernel structure.
    Scalars* sc = (Scalars*)d_ws;
    float* pmax = (float*)((char*)d_ws + 256);
    k_amax<<<MM_BLOCKS, 256, 0, stream>>>(x, pmax, n4);
    k_scalars<<<1, 256, 0, stream>>>(pmax, sc);
    k_row<<<rows / 4, 256, 0, stream>>>(x, out, sc);
}

// Round 4
// 379.574 us; speedup vs baseline: 1.2008x; 1.2008x over previous
//
#include <hip/hip_runtime.h>
#include <math.h>

// I-BERT IntSoftmax, exact-numerics replication of the JAX reference.
// x: (1,12,2048,2048) f32; 24576 rows of S=2048.
// R7: revert cooperative (grid.sync storm + 64-VGPR spill => 287us).
//  - k_amax: 8 independent float4 loads in flight per wave (R4/R5 profile
//    showed VGPR=12 => ONE outstanding load => ~3 TB/s latency-bound).
//  - k_scalars folded into k_row prologue: every block reduces the 2048
//    partials (identical order => identical bits) and derives scalars,
//    readfirstlane-pinned to SGPRs. One launch fewer.

#define ROW_S 2048
#define MM_BLOCKS 2048
#define MM_STRIDE (MM_BLOCKS * 256)

typedef float floatx4 __attribute__((ext_vector_type(4)));

// Markstein: with inv = RN(1/b), returns RN(a/b) bit-exactly.
__device__ __forceinline__ float div_rn(float a, float b, float inv) {
    const float q0 = __fmul_rn(a, inv);
    const float r  = __fmaf_rn(-b, q0, a);
    return __fmaf_rn(r, inv, q0);
}
__device__ __forceinline__ double ddiv_rn(double a, double b, double inv) {
    const double q0 = __dmul_rn(a, inv);
    const double r  = __fma_rn(-b, q0, a);
    return __fma_rn(r, inv, q0);
}

// readfirstlane pins a wave-uniform value into an SGPR (value-preserving).
__device__ __forceinline__ float rfl(float v) {
    return __uint_as_float(__builtin_amdgcn_readfirstlane(__float_as_uint(v)));
}
__device__ __forceinline__ double rfld(double v) {
    union { double d; unsigned long long u; } c;
    c.d = v;
    const unsigned lo = __builtin_amdgcn_readfirstlane((unsigned)c.u);
    const unsigned hi = __builtin_amdgcn_readfirstlane((unsigned)(c.u >> 32));
    c.u = ((unsigned long long)hi << 32) | lo;
    return c.d;
}

// Pass 1: per-block partial max|x|. 8 independent 16B loads per iteration,
// all issued before any consumption => ~8 KB in flight per wave.
__global__ __launch_bounds__(256) void k_amax(const float* __restrict__ x,
                                              float* __restrict__ pmax,
                                              int n4) {
    const int tid = threadIdx.x;
    const float4* x4 = (const float4*)x;
    float am = 0.0f;
    int i = blockIdx.x * 256 + tid;
    // n4 = 12582912, stride = 524288: exactly 3 main iterations, no tail.
    for (; i + 7 * MM_STRIDE < n4; i += 8 * MM_STRIDE) {
        float4 v[8];
#pragma unroll
        for (int u = 0; u < 8; ++u) v[u] = x4[i + u * MM_STRIDE];
        float m[8];
#pragma unroll
        for (int u = 0; u < 8; ++u)
            m[u] = fmaxf(fmaxf(fabsf(v[u].x), fabsf(v[u].y)),
                         fmaxf(fabsf(v[u].z), fabsf(v[u].w)));
        const float a0 = fmaxf(fmaxf(m[0], m[1]), fmaxf(m[2], m[3]));
        const float a1 = fmaxf(fmaxf(m[4], m[5]), fmaxf(m[6], m[7]));
        am = fmaxf(am, fmaxf(a0, a1));
    }
    for (; i < n4; i += MM_STRIDE) {
        const float4 v = x4[i];
        am = fmaxf(am, fmaxf(fmaxf(fabsf(v.x), fabsf(v.y)),
                             fmaxf(fabsf(v.z), fabsf(v.w))));
    }
#pragma unroll
    for (int m = 32; m > 0; m >>= 1) am = fmaxf(am, __shfl_xor(am, m));
    __shared__ float sred[4];
    const int wave = tid >> 6, lane = tid & 63;
    if (lane == 0) sred[wave] = am;
    __syncthreads();
    if (tid == 0)
        pmax[blockIdx.x] = fmaxf(fmaxf(sred[0], sred[1]), fmaxf(sred[2], sred[3]));
}

// Pass 2: one wave per row, 32 elements/lane. Prologue: every block reduces
// the 2048 partials (same order as the old k_scalars => identical bits) and
// derives all scalars in registers (SGPR-pinned).
__global__ __launch_bounds__(256) void k_row(const float* __restrict__ x,
                                             float* __restrict__ out,
                                             const float* __restrict__ pmax) {
    const int tid  = threadIdx.x;
    const int lane = tid & 63, wave = tid >> 6;
    const size_t row = (size_t)blockIdx.x * 4 + wave;
    const floatx4* x4r = (const floatx4*)(x + row * ROW_S);
    floatx4* o4 = (floatx4*)(out + row * ROW_S);

    // issue the row's global loads first; scalar prologue hides under them
    floatx4 v[8];
#pragma unroll
    for (int i = 0; i < 8; ++i) v[i] = x4r[i * 64 + lane];

    // ---- scalars prologue ----
    __shared__ float sred[4];
    float am = 0.0f;
    for (int i = tid; i < MM_BLOCKS; i += 256) am = fmaxf(am, pmax[i]);
#pragma unroll
    for (int m = 32; m > 0; m >>= 1) am = fmaxf(am, __shfl_xor(am, m));
    if (lane == 0) sred[wave] = am;
    __syncthreads();
    const float sabs = fmaxf(fmaxf(sred[0], sred[1]), fmaxf(sred[2], sred[3]));

    // sym_scale(x.min, x.max, 16) via max|x|, all f32 like the reference
    const float sf     = rfl(__fdiv_rn(fmaxf(sabs, 1e-8f), 32767.0f));
    const float x0i    = rfl(floorf(__fdiv_rn((float)(-0.6931), sf)));
    const float sfsq   = __fmul_rn(sf, sf);
    const float b_int  = rfl(floorf(__fdiv_rn((float)(0.96963238 / 0.35815147), sf)));
    const float c_int  = rfl(floorf(__fdiv_rn((float)(1.0 / 0.35815147), sfsq)));
    const float exp_sf = rfl(__fdiv_rn(__fmul_rn((float)(0.35815147), sfsq), 1073741824.0f));
    // global max of exp_int is exactly c_int * 2^30 (row-max element:
    // r=0,q=0 => z=c_int); min>=0, so sym_scale uses this max.
    const float emax   = __fmul_rn(c_int, 1073741824.0f);
    const float act_sf = __fdiv_rn(fmaxf(emax, 1e-8f), 32767.0f);
    // fixedpoint_mul scalar part (f64, per reference)
    const float  nsf = __fdiv_rn(exp_sf, act_sf);
    const double ns  = (double)nsf;
    int E;
    (void)frexp(ns, &E);                       // e = floor(log2(ns)) + 1 == E
    const double m_int      = rfld(rint(ldexp(ns, 31 - E)));
    const double inv_pow    = rfld(ldexp(1.0, E - 31));        // exact pow2
    const double exp_sf_d   = rfld((double)exp_sf);
    const double inv_exp_sf = rfld(1.0 / (double)exp_sf);      // RN f64 recip
    const float  inv_sf     = rfl(__fdiv_rn(1.0f, sf));
    const float  inv_x0     = rfl(__fdiv_rn(1.0f, x0i));
    const float  thirty_x0  = rfl(__fmul_rn(30.0f, x0i));      // exact

    // ---- row body (proven R5 structure) ----
    // raw row max (quant chain is monotone => ximax = quant(raw max), exact)
    float rmax = -INFINITY;
#pragma unroll
    for (int i = 0; i < 8; ++i) {
#pragma unroll
        for (int c = 0; c < 4; ++c) rmax = fmaxf(rmax, v[i][c]);
    }
#pragma unroll
    for (int m = 32; m > 0; m >>= 1) rmax = fmaxf(rmax, __shfl_xor(rmax, m));

    float t = rintf(div_rn(rmax, sf, inv_sf));
    t = fminf(fmaxf(t, -32768.0f), 32767.0f);
    t = __fmul_rn(t, sf);
    const float ximax = div_rn(t, sf, inv_sf);

    float ssum = 0.0f;
#pragma unroll
    for (int i = 0; i < 8; ++i) {
#pragma unroll
        for (int c = 0; c < 4; ++c) {
            // QuantAct(16): x_int = clip(rint(x/sf)); xi = (x_int*sf)/sf
            float q = rintf(div_rn(v[i][c], sf, inv_sf));
            q = fminf(fmaxf(q, -32768.0f), 32767.0f);
            q = __fmul_rn(q, sf);
            const float xi = div_rn(q, sf, inv_sf);
            const float xs = __fsub_rn(xi, ximax);
            const float xm = fmaxf(xs, thirty_x0);
            const float qf = floorf(div_rn(xm, x0i, inv_x0));
            const float r  = __fsub_rn(xm, __fmul_rn(x0i, qf));
            // z = r*(r+b)+c — must NOT contract to FMA (XLA CPU doesn't)
            const float z  = __fadd_rn(__fmul_rn(r, __fadd_rn(r, b_int)), c_int);
            const int   qi = (int)qf;                          // qf in [0,30]
            const float p2 = __int_as_float((157 - qi) << 23); // 2^(30-qi)
            const float ei = fmaxf(floorf(__fmul_rn(z, p2)), 0.0f);
            // fixedpoint_mul in f64 (reference runs in double)
            const double a  = (double)ei;
            const double zi = rint(ddiv_rn(a, exp_sf_d, inv_exp_sf));
            double ovd = rint(__dmul_rn(__dmul_rn(zi, m_int), inv_pow));
            ovd = fmin(fmax(ovd, -32768.0), 32767.0);
            const float e16 = (float)ovd;   // integer-valued, exact
            v[i][c] = e16;
            ssum += e16;   // non-neg ints, row sum < 2^24 -> order-free exact
        }
    }
#pragma unroll
    for (int m = 32; m > 0; m >>= 1) ssum += __shfl_xor(ssum, m);
    const float factor = floorf(__fdiv_rn(4294967296.0f, ssum));

#pragma unroll
    for (int i = 0; i < 8; ++i) {
        floatx4 w;
#pragma unroll
        for (int c = 0; c < 4; ++c) {
            // /2^24 == *2^-24 exactly (pow2), then *2^-8 exact
            const float oi = floorf(__fmul_rn(__fmul_rn(v[i][c], factor),
                                              5.9604644775390625e-8f));
            w[c] = __fmul_rn(oi, 0.00390625f);
        }
        __builtin_nontemporal_store(w, &o4[i * 64 + lane]);
    }
}

extern "C" void kernel_launch(void* const* d_in, const int* in_sizes, int n_in,
                              void* d_out, int out_size, void* d_ws, size_t ws_size,
                              hipStream_t stream) {
    const float* x = (const float*)d_in[0];
    float* out = (float*)d_out;
    const int n = in_sizes[0];          // 50331648
    const int rows = n / ROW_S;         // 24576

    float* pmax = (float*)d_ws;         // MM_BLOCKS floats

    k_amax<<<MM_BLOCKS, 256, 0, stream>>>(x, pmax, n / 4);
    k_row<<<rows / 4, 256, 0, stream>>>(x, out, pmax);
}

// Round 5
// 363.415 us; speedup vs baseline: 1.2542x; 1.0445x over previous
//
#include <hip/hip_runtime.h>
#include <math.h>

// I-BERT IntSoftmax, exact-numerics replication of the JAX reference.
// x: (1,12,2048,2048) f32; 24576 rows of S=2048.
// R8: R5 structure (separate 1-block k_scalars — R7's per-block scalar
//     prologue cost ~22us across 6144 blocks) + R7's 8-deep-MLP k_amax
//     (R4/R5 profiles showed VGPR=12 => one outstanding load => ~3 TB/s).
//     Clean A/B vs R5: only k_amax body differs.

#define ROW_S 2048
#define MM_BLOCKS 2048
#define MM_STRIDE (MM_BLOCKS * 256)

typedef float floatx4 __attribute__((ext_vector_type(4)));

struct Scalars {
    double exp_sf_d;   // exp_sf (f64) — fixedpoint_mul divisor
    double inv_exp_sf; // RN(1/exp_sf_d), f64 (Markstein reciprocal)
    double m_int;      // 31-bit mantissa (f64)
    double inv_pow;    // 2^(e-31) exact
    float  sf;         // activation scale
    float  inv_sf;     // RN(1/sf)
    float  x0_int;     // floor(-0.6931/sf)
    float  inv_x0;     // RN(1/x0_int)
    float  b_int;      // floor(COEF1/sf)
    float  c_int;      // floor(COEF2/sf^2)
    float  thirty_x0;  // 30 * x0_int (exact)
    float  _pad;
};

// Markstein: with inv = RN(1/b), returns RN(a/b) bit-exactly.
__device__ __forceinline__ float div_rn(float a, float b, float inv) {
    const float q0 = __fmul_rn(a, inv);
    const float r  = __fmaf_rn(-b, q0, a);
    return __fmaf_rn(r, inv, q0);
}
__device__ __forceinline__ double ddiv_rn(double a, double b, double inv) {
    const double q0 = __dmul_rn(a, inv);
    const double r  = __fma_rn(-b, q0, a);
    return __fma_rn(r, inv, q0);
}

// Pass 1: per-block partial max|x|. 8 independent 16B loads per iteration,
// all issued before any consumption => ~8 KB in flight per wave (MLP).
__global__ __launch_bounds__(256) void k_amax(const float* __restrict__ x,
                                              float* __restrict__ pmax,
                                              int n4) {
    const int tid = threadIdx.x;
    const float4* x4 = (const float4*)x;
    float am = 0.0f;
    int i = blockIdx.x * 256 + tid;
    // n4 = 12582912 = 3 * (8*MM_STRIDE): exactly 3 main iterations, no tail.
    for (; i + 7 * MM_STRIDE < n4; i += 8 * MM_STRIDE) {
        float4 v[8];
#pragma unroll
        for (int u = 0; u < 8; ++u) v[u] = x4[i + u * MM_STRIDE];
        float m[8];
#pragma unroll
        for (int u = 0; u < 8; ++u)
            m[u] = fmaxf(fmaxf(fabsf(v[u].x), fabsf(v[u].y)),
                         fmaxf(fabsf(v[u].z), fabsf(v[u].w)));
        const float a0 = fmaxf(fmaxf(m[0], m[1]), fmaxf(m[2], m[3]));
        const float a1 = fmaxf(fmaxf(m[4], m[5]), fmaxf(m[6], m[7]));
        am = fmaxf(am, fmaxf(a0, a1));
    }
    for (; i < n4; i += MM_STRIDE) {
        const float4 v = x4[i];
        am = fmaxf(am, fmaxf(fmaxf(fabsf(v.x), fabsf(v.y)),
                             fmaxf(fabsf(v.z), fabsf(v.w))));
    }
#pragma unroll
    for (int m = 32; m > 0; m >>= 1) am = fmaxf(am, __shfl_xor(am, m));
    __shared__ float sred[4];
    const int wave = tid >> 6, lane = tid & 63;
    if (lane == 0) sred[wave] = am;
    __syncthreads();
    if (tid == 0)
        pmax[blockIdx.x] = fmaxf(fmaxf(sred[0], sred[1]), fmaxf(sred[2], sred[3]));
}

// Pass 1b: single block reduces 2048 partials and derives all Scalars ONCE.
__global__ __launch_bounds__(256) void k_scalars(const float* __restrict__ pmax,
                                                 Scalars* __restrict__ sc) {
    const int tid = threadIdx.x;
    float am = 0.0f;
    for (int i = tid; i < MM_BLOCKS; i += 256) am = fmaxf(am, pmax[i]);
#pragma unroll
    for (int m = 32; m > 0; m >>= 1) am = fmaxf(am, __shfl_xor(am, m));
    __shared__ float sred[4];
    const int wave = tid >> 6, lane = tid & 63;
    if (lane == 0) sred[wave] = am;
    __syncthreads();
    if (tid == 0) {
        const float sabs = fmaxf(fmaxf(sred[0], sred[1]), fmaxf(sred[2], sred[3]));
        // sym_scale(x.min, x.max, 16) via max|x|, all f32 like the reference
        const float sf    = __fdiv_rn(fmaxf(sabs, 1e-8f), 32767.0f);
        const float x0i   = floorf(__fdiv_rn((float)(-0.6931), sf));
        const float sfsq  = __fmul_rn(sf, sf);
        const float b_int = floorf(__fdiv_rn((float)(0.96963238 / 0.35815147), sf));
        const float c_int = floorf(__fdiv_rn((float)(1.0 / 0.35815147), sfsq));
        const float exp_sf = __fdiv_rn(__fmul_rn((float)(0.35815147), sfsq), 1073741824.0f);
        // global max of exp_int is exactly c_int * 2^30 (row-max element:
        // r=0,q=0 => z=c_int); min>=0, so sym_scale uses this max.
        const float emax   = __fmul_rn(c_int, 1073741824.0f);
        const float act_sf = __fdiv_rn(fmaxf(emax, 1e-8f), 32767.0f);
        // fixedpoint_mul scalar part (f64, per reference)
        const float  nsf = __fdiv_rn(exp_sf, act_sf);
        const double ns  = (double)nsf;
        int E;
        (void)frexp(ns, &E);                 // e = floor(log2(ns)) + 1 == E
        const double m_int = rint(ldexp(ns, 31 - E));
        sc->exp_sf_d   = (double)exp_sf;
        sc->inv_exp_sf = 1.0 / (double)exp_sf;
        sc->m_int      = m_int;
        sc->inv_pow    = ldexp(1.0, E - 31);          // exact pow2
        sc->sf         = sf;
        sc->inv_sf     = __fdiv_rn(1.0f, sf);
        sc->x0_int     = x0i;
        sc->inv_x0     = __fdiv_rn(1.0f, x0i);
        sc->b_int      = b_int;
        sc->c_int      = c_int;
        sc->thirty_x0  = __fmul_rn(30.0f, x0i);       // exact (int < 2^24)
    }
}

// Pass 2: one wave per row, 32 elements/lane, no LDS, no __syncthreads.
__global__ __launch_bounds__(256) void k_row(const float* __restrict__ x,
                                             float* __restrict__ out,
                                             const Scalars* __restrict__ scp) {
    const int lane = threadIdx.x & 63;
    const int wave = threadIdx.x >> 6;
    const size_t row = (size_t)blockIdx.x * 4 + wave;
    const floatx4* x4 = (const floatx4*)(x + row * ROW_S);
    floatx4* o4 = (floatx4*)(out + row * ROW_S);

    // issue all global loads first; scalar struct load overlaps
    floatx4 v[8];
#pragma unroll
    for (int i = 0; i < 8; ++i) v[i] = x4[i * 64 + lane];

    const Scalars sc = *scp;
    const float sf = sc.sf, inv_sf = sc.inv_sf;

    // raw row max (quant chain is monotone => ximax = quant(raw max), exact)
    float rmax = -INFINITY;
#pragma unroll
    for (int i = 0; i < 8; ++i) {
#pragma unroll
        for (int c = 0; c < 4; ++c) rmax = fmaxf(rmax, v[i][c]);
    }
#pragma unroll
    for (int m = 32; m > 0; m >>= 1) rmax = fmaxf(rmax, __shfl_xor(rmax, m));

    float t = rintf(div_rn(rmax, sf, inv_sf));
    t = fminf(fmaxf(t, -32768.0f), 32767.0f);
    t = __fmul_rn(t, sf);
    const float ximax = div_rn(t, sf, inv_sf);

    float ssum = 0.0f;
#pragma unroll
    for (int i = 0; i < 8; ++i) {
#pragma unroll
        for (int c = 0; c < 4; ++c) {
            // QuantAct(16): x_int = clip(rint(x/sf)); xi = (x_int*sf)/sf (RN, no FMA)
            float q = rintf(div_rn(v[i][c], sf, inv_sf));
            q = fminf(fmaxf(q, -32768.0f), 32767.0f);
            q = __fmul_rn(q, sf);
            const float xi = div_rn(q, sf, inv_sf);
            const float xs = __fsub_rn(xi, ximax);
            const float xm = fmaxf(xs, sc.thirty_x0);
            const float qf = floorf(div_rn(xm, sc.x0_int, sc.inv_x0));
            const float r  = __fsub_rn(xm, __fmul_rn(sc.x0_int, qf));
            // z = r*(r+b)+c — must NOT contract to FMA (XLA CPU doesn't)
            const float z  = __fadd_rn(__fmul_rn(r, __fadd_rn(r, sc.b_int)), sc.c_int);
            const int   qi = (int)qf;                          // qf in [0,30]
            const float p2 = __int_as_float((157 - qi) << 23); // exactly 2^(30-qi)
            const float ei = fmaxf(floorf(__fmul_rn(z, p2)), 0.0f);
            // fixedpoint_mul in f64 (reference runs in double)
            const double a  = (double)ei;
            const double zi = rint(ddiv_rn(a, sc.exp_sf_d, sc.inv_exp_sf));
            double ovd = rint(__dmul_rn(__dmul_rn(zi, sc.m_int), sc.inv_pow));
            ovd = fmin(fmax(ovd, -32768.0), 32767.0);
            const float e16 = (float)ovd;   // integer-valued, exact
            v[i][c] = e16;
            ssum += e16;   // non-negative ints, row sum < 2^24 -> order-free exact
        }
    }
#pragma unroll
    for (int m = 32; m > 0; m >>= 1) ssum += __shfl_xor(ssum, m);
    const float factor = floorf(__fdiv_rn(4294967296.0f, ssum));

#pragma unroll
    for (int i = 0; i < 8; ++i) {
        floatx4 w;
#pragma unroll
        for (int c = 0; c < 4; ++c) {
            // /2^24 == *2^-24 exactly (pow2), then *2^-8 exact
            const float oi = floorf(__fmul_rn(__fmul_rn(v[i][c], factor), 5.9604644775390625e-8f));
            w[c] = __fmul_rn(oi, 0.00390625f);
        }
        __builtin_nontemporal_store(w, &o4[i * 64 + lane]);
    }
}

extern "C" void kernel_launch(void* const* d_in, const int* in_sizes, int n_in,
                              void* d_out, int out_size, void* d_ws, size_t ws_size,
                              hipStream_t stream) {
    const float* x = (const float*)d_in[0];
    float* out = (float*)d_out;
    const int n = in_sizes[0];          // 50331648
    const int rows = n / ROW_S;         // 24576

    Scalars* sc = (Scalars*)d_ws;
    float* pmax = (float*)((char*)d_ws + 256);

    k_amax<<<MM_BLOCKS, 256, 0, stream>>>(x, pmax, n / 4);
    k_scalars<<<1, 256, 0, stream>>>(pmax, sc);
    k_row<<<rows / 4, 256, 0, stream>>>(x, out, sc);
}

// Round 6
// 359.198 us; speedup vs baseline: 1.2690x; 1.0117x over previous
//
#include <hip/hip_runtime.h>
#include <math.h>

// I-BERT IntSoftmax, exact-numerics replication of the JAX reference.
// x: (1,12,2048,2048) f32; 24576 rows of S=2048.
// R9: k_amax rewritten — contiguous 96KB per-block chunks (was 8MB-stride
//     grid-stride) + 12-deep independent float4 batches, dual accumulator
//     trees, VGPR kept <64 for full occupancy. k_scalars/k_row unchanged
//     (proven R5 bodies). If this doesn't move k_amax (~70us -> ~35us),
//     the read path is hard-capped and the structure is at its floor.

#define ROW_S 2048
#define MM_BLOCKS 2048
#define MM_STRIDE (MM_BLOCKS * 256)

typedef float floatx4 __attribute__((ext_vector_type(4)));

struct Scalars {
    double exp_sf_d;   // exp_sf (f64) — fixedpoint_mul divisor
    double inv_exp_sf; // RN(1/exp_sf_d), f64 (Markstein reciprocal)
    double m_int;      // 31-bit mantissa (f64)
    double inv_pow;    // 2^(e-31) exact
    float  sf;         // activation scale
    float  inv_sf;     // RN(1/sf)
    float  x0_int;     // floor(-0.6931/sf)
    float  inv_x0;     // RN(1/x0_int)
    float  b_int;      // floor(COEF1/sf)
    float  c_int;      // floor(COEF2/sf^2)
    float  thirty_x0;  // 30 * x0_int (exact)
    float  _pad;
};

// Markstein: with inv = RN(1/b), returns RN(a/b) bit-exactly.
__device__ __forceinline__ float div_rn(float a, float b, float inv) {
    const float q0 = __fmul_rn(a, inv);
    const float r  = __fmaf_rn(-b, q0, a);
    return __fmaf_rn(r, inv, q0);
}
__device__ __forceinline__ double ddiv_rn(double a, double b, double inv) {
    const double q0 = __dmul_rn(a, inv);
    const double r  = __fma_rn(-b, q0, a);
    return __fma_rn(r, inv, q0);
}

__device__ __forceinline__ float amax4(float4 v) {
    return fmaxf(fmaxf(fabsf(v.x), fabsf(v.y)), fmaxf(fabsf(v.z), fabsf(v.w)));
}

// Pass 1: per-block partial max|x| over a CONTIGUOUS chunk.
// 12 independent 16B loads per batch => 12 KB in flight per wave.
__global__ __launch_bounds__(256) void k_amax(const float* __restrict__ x,
                                              float* __restrict__ pmax,
                                              int n4) {
    const int tid = threadIdx.x;
    const float4* x4 = (const float4*)x;
    const int chunk = n4 / MM_BLOCKS;          // 6144 float4 = 96 KB per block
    const int base  = blockIdx.x * chunk;
    float am0 = 0.0f, am1 = 0.0f;

    int k = tid;
    // chunk = 6144 = 2 * (12*256): exactly 2 main batches, no inner tail.
    for (; k + 11 * 256 < chunk; k += 12 * 256) {
        float4 v[12];
#pragma unroll
        for (int u = 0; u < 12; ++u) v[u] = x4[base + k + u * 256];
        float m[12];
#pragma unroll
        for (int u = 0; u < 12; ++u) m[u] = amax4(v[u]);
        const float a = fmaxf(fmaxf(fmaxf(m[0], m[1]), fmaxf(m[2], m[3])),
                              fmaxf(m[4], m[5]));
        const float b = fmaxf(fmaxf(fmaxf(m[6], m[7]), fmaxf(m[8], m[9])),
                              fmaxf(m[10], m[11]));
        am0 = fmaxf(am0, a);
        am1 = fmaxf(am1, b);
    }
    for (; k < chunk; k += 256) am0 = fmaxf(am0, amax4(x4[base + k]));
    // global tail if n4 % MM_BLOCKS != 0 (empty for this shape)
    for (int i = MM_BLOCKS * chunk + blockIdx.x * 256 + tid; i < n4; i += MM_STRIDE)
        am0 = fmaxf(am0, amax4(x4[i]));

    float am = fmaxf(am0, am1);
#pragma unroll
    for (int m = 32; m > 0; m >>= 1) am = fmaxf(am, __shfl_xor(am, m));
    __shared__ float sred[4];
    const int wave = tid >> 6, lane = tid & 63;
    if (lane == 0) sred[wave] = am;
    __syncthreads();
    if (tid == 0)
        pmax[blockIdx.x] = fmaxf(fmaxf(sred[0], sred[1]), fmaxf(sred[2], sred[3]));
}

// Pass 1b: single block reduces 2048 partials and derives all Scalars ONCE.
__global__ __launch_bounds__(256) void k_scalars(const float* __restrict__ pmax,
                                                 Scalars* __restrict__ sc) {
    const int tid = threadIdx.x;
    float am = 0.0f;
    for (int i = tid; i < MM_BLOCKS; i += 256) am = fmaxf(am, pmax[i]);
#pragma unroll
    for (int m = 32; m > 0; m >>= 1) am = fmaxf(am, __shfl_xor(am, m));
    __shared__ float sred[4];
    const int wave = tid >> 6, lane = tid & 63;
    if (lane == 0) sred[wave] = am;
    __syncthreads();
    if (tid == 0) {
        const float sabs = fmaxf(fmaxf(sred[0], sred[1]), fmaxf(sred[2], sred[3]));
        // sym_scale(x.min, x.max, 16) via max|x|, all f32 like the reference
        const float sf    = __fdiv_rn(fmaxf(sabs, 1e-8f), 32767.0f);
        const float x0i   = floorf(__fdiv_rn((float)(-0.6931), sf));
        const float sfsq  = __fmul_rn(sf, sf);
        const float b_int = floorf(__fdiv_rn((float)(0.96963238 / 0.35815147), sf));
        const float c_int = floorf(__fdiv_rn((float)(1.0 / 0.35815147), sfsq));
        const float exp_sf = __fdiv_rn(__fmul_rn((float)(0.35815147), sfsq), 1073741824.0f);
        // global max of exp_int is exactly c_int * 2^30 (row-max element:
        // r=0,q=0 => z=c_int); min>=0, so sym_scale uses this max.
        const float emax   = __fmul_rn(c_int, 1073741824.0f);
        const float act_sf = __fdiv_rn(fmaxf(emax, 1e-8f), 32767.0f);
        // fixedpoint_mul scalar part (f64, per reference)
        const float  nsf = __fdiv_rn(exp_sf, act_sf);
        const double ns  = (double)nsf;
        int E;
        (void)frexp(ns, &E);                 // e = floor(log2(ns)) + 1 == E
        const double m_int = rint(ldexp(ns, 31 - E));
        sc->exp_sf_d   = (double)exp_sf;
        sc->inv_exp_sf = 1.0 / (double)exp_sf;
        sc->m_int      = m_int;
        sc->inv_pow    = ldexp(1.0, E - 31);          // exact pow2
        sc->sf         = sf;
        sc->inv_sf     = __fdiv_rn(1.0f, sf);
        sc->x0_int     = x0i;
        sc->inv_x0     = __fdiv_rn(1.0f, x0i);
        sc->b_int      = b_int;
        sc->c_int      = c_int;
        sc->thirty_x0  = __fmul_rn(30.0f, x0i);       // exact (int < 2^24)
    }
}

// Pass 2: one wave per row, 32 elements/lane, no LDS, no __syncthreads.
__global__ __launch_bounds__(256) void k_row(const float* __restrict__ x,
                                             float* __restrict__ out,
                                             const Scalars* __restrict__ scp) {
    const int lane = threadIdx.x & 63;
    const int wave = threadIdx.x >> 6;
    const size_t row = (size_t)blockIdx.x * 4 + wave;
    const floatx4* x4 = (const floatx4*)(x + row * ROW_S);
    floatx4* o4 = (floatx4*)(out + row * ROW_S);

    // issue all global loads first; scalar struct load overlaps
    floatx4 v[8];
#pragma unroll
    for (int i = 0; i < 8; ++i) v[i] = x4[i * 64 + lane];

    const Scalars sc = *scp;
    const float sf = sc.sf, inv_sf = sc.inv_sf;

    // raw row max (quant chain is monotone => ximax = quant(raw max), exact)
    float rmax = -INFINITY;
#pragma unroll
    for (int i = 0; i < 8; ++i) {
#pragma unroll
        for (int c = 0; c < 4; ++c) rmax = fmaxf(rmax, v[i][c]);
    }
#pragma unroll
    for (int m = 32; m > 0; m >>= 1) rmax = fmaxf(rmax, __shfl_xor(rmax, m));

    float t = rintf(div_rn(rmax, sf, inv_sf));
    t = fminf(fmaxf(t, -32768.0f), 32767.0f);
    t = __fmul_rn(t, sf);
    const float ximax = div_rn(t, sf, inv_sf);

    float ssum = 0.0f;
#pragma unroll
    for (int i = 0; i < 8; ++i) {
#pragma unroll
        for (int c = 0; c < 4; ++c) {
            // QuantAct(16): x_int = clip(rint(x/sf)); xi = (x_int*sf)/sf (RN, no FMA)
            float q = rintf(div_rn(v[i][c], sf, inv_sf));
            q = fminf(fmaxf(q, -32768.0f), 32767.0f);
            q = __fmul_rn(q, sf);
            const float xi = div_rn(q, sf, inv_sf);
            const float xs = __fsub_rn(xi, ximax);
            const float xm = fmaxf(xs, sc.thirty_x0);
            const float qf = floorf(div_rn(xm, sc.x0_int, sc.inv_x0));
            const float r  = __fsub_rn(xm, __fmul_rn(sc.x0_int, qf));
            // z = r*(r+b)+c — must NOT contract to FMA (XLA CPU doesn't)
            const float z  = __fadd_rn(__fmul_rn(r, __fadd_rn(r, sc.b_int)), sc.c_int);
            const int   qi = (int)qf;                          // qf in [0,30]
            const float p2 = __int_as_float((157 - qi) << 23); // exactly 2^(30-qi)
            const float ei = fmaxf(floorf(__fmul_rn(z, p2)), 0.0f);
            // fixedpoint_mul in f64 (reference runs in double)
            const double a  = (double)ei;
            const double zi = rint(ddiv_rn(a, sc.exp_sf_d, sc.inv_exp_sf));
            double ovd = rint(__dmul_rn(__dmul_rn(zi, sc.m_int), sc.inv_pow));
            ovd = fmin(fmax(ovd, -32768.0), 32767.0);
            const float e16 = (float)ovd;   // integer-valued, exact
            v[i][c] = e16;
            ssum += e16;   // non-negative ints, row sum < 2^24 -> order-free exact
        }
    }
#pragma unroll
    for (int m = 32; m > 0; m >>= 1) ssum += __shfl_xor(ssum, m);
    const float factor = floorf(__fdiv_rn(4294967296.0f, ssum));

#pragma unroll
    for (int i = 0; i < 8; ++i) {
        floatx4 w;
#pragma unroll
        for (int c = 0; c < 4; ++c) {
            // /2^24 == *2^-24 exactly (pow2), then *2^-8 exact
            const float oi = floorf(__fmul_rn(__fmul_rn(v[i][c], factor), 5.9604644775390625e-8f));
            w[c] = __fmul_rn(oi, 0.00390625f);
        }
        __builtin_nontemporal_store(w, &o4[i * 64 + lane]);
    }
}

extern "C" void kernel_launch(void* const* d_in, const int* in_sizes, int n_in,
                              void* d_out, int out_size, void* d_ws, size_t ws_size,
                              hipStream_t stream) {
    const float* x = (const float*)d_in[0];
    float* out = (float*)d_out;
    const int n = in_sizes[0];          // 50331648
    const int rows = n / ROW_S;         // 24576

    Scalars* sc = (Scalars*)d_ws;
    float* pmax = (float*)((char*)d_ws + 256);

    k_amax<<<MM_BLOCKS, 256, 0, stream>>>(x, pmax, n / 4);
    k_scalars<<<1, 256, 0, stream>>>(pmax, sc);
    k_row<<<rows / 4, 256, 0, stream>>>(x, out, sc);
}